// Round 9
// baseline (408.280 us; speedup 1.0000x reference)
//
#include <hip/hip_runtime.h>
#include <hip/hip_cooperative_groups.h>
namespace cg = cooperative_groups;

typedef __bf16 bf16x8 __attribute__((ext_vector_type(8)));
typedef float  f32x4  __attribute__((ext_vector_type(4)));

__device__ __forceinline__ unsigned short f2bf(float f){
    union { float f; unsigned u; } v; v.f = f;
    v.u += 0x7fffu + ((v.u >> 16) & 1u);          // RNE
    return (unsigned short)(v.u >> 16);
}
__device__ __forceinline__ unsigned short f2bf_trunc(float f){
    union { float f; unsigned u; } v; v.f = f;
    return (unsigned short)(v.u >> 16);
}
// async 16B global->LDS. lptr wave-uniform; HW dest = lptr + lane*16.
__device__ __forceinline__ void gl2lds16(const unsigned short* g, unsigned short* l){
    __builtin_amdgcn_global_load_lds(
        (const __attribute__((address_space(1))) void*)g,
        (__attribute__((address_space(3))) void*)l, 16, 0, 0);
}

struct SMemG { unsigned short a[128*64]; unsigned short b[128*64]; };
struct SMemF { unsigned short k[2][64*64]; unsigned short v[2][64*64]; unsigned short p[4][16*72]; };
union SMem { float tr[64*72]; SMemG g; SMemF f; };

// ============ R8-exact GEMM mainloop: 128x128 tile, K=512 =====================
// XOR-chunk swizzle: chunk c of row stored at position c^(row&7).
__device__ __forceinline__ void gemm_mainloop(const unsigned short* __restrict__ A,
                                              const unsigned short* __restrict__ Bm,
                                              unsigned short* a_s, unsigned short* b_s,
                                              int m0, int n0, int tid, f32x4 acc[4][4]){
    const int wave = tid >> 6, lane = tid & 63;
    const int l15 = lane & 15, l4 = lane >> 4;
    const int mw = (wave >> 1) * 64, nw = (wave & 1) * 64;
    const int r8 = lane >> 3, c8l = lane & 7;
    const int csw = (c8l ^ r8) * 8;                // swizzled source chunk (shorts)
    const int rp = l15 & 7;

    for (int k0 = 0; k0 < 512; k0 += 64){
        #pragma unroll
        for (int i = 0; i < 4; i++){
            int rg = i * 4 + wave;                 // 0..15 -> 8-row group
            int row = rg * 8 + r8;
            gl2lds16(A  + (size_t)(m0 + row) * 512 + k0 + csw, a_s + rg * 512);
            gl2lds16(Bm + (size_t)(n0 + row) * 512 + k0 + csw, b_s + rg * 512);
        }
        __syncthreads();
        #pragma unroll
        for (int kk = 0; kk < 2; kk++){
            bf16x8 af[4], bfr[4];
            #pragma unroll
            for (int mt = 0; mt < 4; mt++)
                af[mt] = *(const bf16x8*)&a_s[(mw + mt*16 + l15)*64 + (((kk*4) + l4) ^ rp)*8];
            #pragma unroll
            for (int ct = 0; ct < 4; ct++)
                bfr[ct] = *(const bf16x8*)&b_s[(nw + ct*16 + l15)*64 + (((kk*4) + l4) ^ rp)*8];
            #pragma unroll
            for (int mt = 0; mt < 4; mt++)
                #pragma unroll
                for (int ct = 0; ct < 4; ct++)
                    acc[mt][ct] = __builtin_amdgcn_mfma_f32_16x16x32_bf16(
                        af[mt], bfr[ct], acc[mt][ct], 0, 0, 0);
        }
        __syncthreads();
    }
}

// ---------------- R8-exact qkv epilogue + tile body, shared by both paths -----
__device__ __forceinline__ void qkv_tile(int z, int bid2,
                                         const unsigned short* xt, const unsigned short* ct,
                                         const unsigned short* wq, const unsigned short* wk,
                                         const unsigned short* wv,
                                         const float* bq_, const float* bk_, const float* bv_,
                                         unsigned short* qt, unsigned short* kt, unsigned short* vct,
                                         unsigned short* a_s, unsigned short* b_s, int tid){
    const unsigned short *A, *Bm;
    int m0, n0;
    if (z == 0){ A = xt; Bm = wq; m0 = (bid2 >> 2)*128; n0 = (bid2 & 3)*128; }
    else if (z == 1){ A = ct; Bm = wk; m0 = (bid2 >> 2)*128; n0 = (bid2 & 3)*128; }
    else { A = wv; Bm = ct; m0 = (bid2 & 3)*128; n0 = (bid2 >> 2)*128; }
    const int wave = tid >> 6, lane = tid & 63;
    const int l15 = lane & 15, l4 = lane >> 4;
    const int mw = (wave >> 1) * 64, nw = (wave & 1) * 64;
    const f32x4 vzero = {0.f, 0.f, 0.f, 0.f};
    f32x4 acc[4][4];
    #pragma unroll
    for (int i = 0; i < 4; i++)
        #pragma unroll
        for (int j = 0; j < 4; j++) acc[i][j] = vzero;

    gemm_mainloop(A, Bm, a_s, b_s, m0, n0, tid, acc);

    if (z < 2){
        unsigned short* out = (z == 0) ? qt : kt;
        const float* bias = (z == 0) ? bq_ : bk_;
        // q pre-scaled by (1/8)*log2(e) so flash uses exp2 directly
        const float osc = (z == 0) ? 0.1803368801111137f : 1.0f;
        float bv4[4];
        #pragma unroll
        for (int ct2 = 0; ct2 < 4; ct2++) bv4[ct2] = bias[n0 + nw + ct2*16 + l15];
        const float theta = __powf(10000.0f, -(float)l15 * (1.0f / 16.0f));
        #pragma unroll
        for (int mt = 0; mt < 4; mt++){
            #pragma unroll
            for (int rr = 0; rr < 4; rr++){
                int row = m0 + mw + mt*16 + l4*4 + rr;     // flat b*1024+t
                int t = row & 1023;
                float v[4];
                #pragma unroll
                for (int ct2 = 0; ct2 < 4; ct2++) v[ct2] = acc[mt][ct2][rr] + bv4[ct2];
                float sn, cn;
                __sincosf((float)t * theta, &sn, &cn);
                float r0 = v[0] * cn - v[1] * sn;
                float r1 = v[1] * cn + v[0] * sn;
                v[0] = r0; v[1] = r1;
                #pragma unroll
                for (int ct2 = 0; ct2 < 4; ct2++)
                    out[(size_t)row * 512 + n0 + nw + ct2*16 + l15] = f2bf(v[ct2] * osc);
            }
        }
    } else {
        #pragma unroll
        for (int mt = 0; mt < 4; mt++){
            #pragma unroll
            for (int rr = 0; rr < 4; rr++){
                int row = m0 + mw + mt*16 + l4*4 + rr;     // o index
                float bb = bv_[row];
                #pragma unroll
                for (int ct2 = 0; ct2 < 4; ct2++){
                    int n = n0 + nw + ct2*16 + l15;        // flat b*1024+t
                    size_t oaddr = (size_t)(n >> 10) * 524288 + (size_t)row * 1024 + (n & 1023);
                    vct[oaddr] = f2bf(acc[mt][ct2][rr] + bb);
                }
            }
        }
    }
}

// ---------------- R8-exact flash tile body ------------------------------------
__device__ __forceinline__ void flash_tile(int b, int h, int q0,
                                           const unsigned short* qt, const unsigned short* kt,
                                           const unsigned short* vct, unsigned short* attnT,
                                           SMemF* sf, int tid){
    const int wave = tid >> 6, lane = tid & 63;
    const int l15 = lane & 15, l4 = lane >> 4;
    const int r8 = lane >> 3, c8l = lane & 7;
    const int csw = (c8l ^ r8) * 8;
    const int rp = l15 & 7;
    const f32x4 vzero = {0.f, 0.f, 0.f, 0.f};
    const unsigned short* kbase = kt  + (size_t)(b*1024)*512 + h*64;
    const unsigned short* vbase = vct + (size_t)(b*512 + h*64)*1024;

    bf16x8 qf[2][2];
    #pragma unroll
    for (int st = 0; st < 2; st++)
        #pragma unroll
        for (int kh = 0; kh < 2; kh++)
            qf[st][kh] = *(const bf16x8*)(qt + (size_t)(b*1024 + q0 + wave*32 + st*16 + l15)*512
                                             + h*64 + kh*32 + l4*8);
    f32x4 o_acc[2][4], l_acc[2];
    #pragma unroll
    for (int st = 0; st < 2; st++){
        l_acc[st] = vzero;
        #pragma unroll
        for (int dt = 0; dt < 4; dt++) o_acc[st][dt] = vzero;
    }
    const __bf16 one_bf = (__bf16)1.0f;
    const bf16x8 ones = {one_bf, one_bf, one_bf, one_bf, one_bf, one_bf, one_bf, one_bf};

    auto stage = [&](int tile, int buf){
        const int s0n = tile * 64;
        #pragma unroll
        for (int i = 0; i < 2; i++){
            int rg = i * 4 + wave;
            int row = rg * 8 + r8;
            gl2lds16(kbase + (size_t)(s0n + row)*512 + csw, &sf->k[buf][rg*512]);
            gl2lds16(vbase + (size_t)row*1024 + s0n + csw, &sf->v[buf][rg*512]);
        }
    };
    stage(0, 0);
    __syncthreads();

    for (int it = 0; it < 16; ++it){
        const int cur = it & 1;
        if (it < 15) stage(it + 1, cur ^ 1);
        bf16x8 kf[2][4], vf[2][4];
        #pragma unroll
        for (int kh = 0; kh < 2; kh++)
            #pragma unroll
            for (int ct = 0; ct < 4; ct++)
                kf[kh][ct] = *(const bf16x8*)&sf->k[cur][(ct*16 + l15)*64 + ((kh*4 + l4) ^ rp)*8];
        #pragma unroll
        for (int sh = 0; sh < 2; sh++)
            #pragma unroll
            for (int dt = 0; dt < 4; dt++)
                vf[sh][dt] = *(const bf16x8*)&sf->v[cur][(dt*16 + l15)*64 + ((sh*4 + l4) ^ rp)*8];
        #pragma unroll
        for (int st = 0; st < 2; st++){
            f32x4 sa[4];
            #pragma unroll
            for (int ct = 0; ct < 4; ct++) sa[ct] = vzero;
            #pragma unroll
            for (int kh = 0; kh < 2; kh++)
                #pragma unroll
                for (int ct = 0; ct < 4; ct++)
                    sa[ct] = __builtin_amdgcn_mfma_f32_16x16x32_bf16(qf[st][kh], kf[kh][ct], sa[ct], 0, 0, 0);
            #pragma unroll
            for (int ct = 0; ct < 4; ct++)
                #pragma unroll
                for (int rr = 0; rr < 4; rr++)
                    sa[ct][rr] = exp2f(sa[ct][rr]);        // q carries log2e/8
            #pragma unroll
            for (int ct = 0; ct < 4; ct++)
                #pragma unroll
                for (int rr = 0; rr < 4; rr++)
                    sf->p[wave][(l4*4 + rr)*72 + ct*16 + l15] = f2bf_trunc(sa[ct][rr]);
            bf16x8 ap0 = *(const bf16x8*)&sf->p[wave][l15*72 + l4*8];
            bf16x8 ap1 = *(const bf16x8*)&sf->p[wave][l15*72 + 32 + l4*8];
            l_acc[st] = __builtin_amdgcn_mfma_f32_16x16x32_bf16(ap0, ones, l_acc[st], 0, 0, 0);
            l_acc[st] = __builtin_amdgcn_mfma_f32_16x16x32_bf16(ap1, ones, l_acc[st], 0, 0, 0);
            #pragma unroll
            for (int dt = 0; dt < 4; dt++){
                o_acc[st][dt] = __builtin_amdgcn_mfma_f32_16x16x32_bf16(ap0, vf[0][dt], o_acc[st][dt], 0, 0, 0);
                o_acc[st][dt] = __builtin_amdgcn_mfma_f32_16x16x32_bf16(ap1, vf[1][dt], o_acc[st][dt], 0, 0, 0);
            }
        }
        __syncthreads();
    }
    #pragma unroll
    for (int st = 0; st < 2; st++){
        float rl[4];
        #pragma unroll
        for (int rr = 0; rr < 4; rr++) rl[rr] = __builtin_amdgcn_rcpf(l_acc[st][rr]);
        #pragma unroll
        for (int dt = 0; dt < 4; dt++)
            #pragma unroll
            for (int rr = 0; rr < 4; rr++){
                int row = q0 + wave*32 + st*16 + l4*4 + rr;
                attnT[(size_t)(b*1024 + row)*512 + h*64 + dt*16 + l15] = f2bf(o_acc[st][dt][rr] * rl[rr]);
            }
    }
}

// ---------------- R8-exact gemm_o tile body -----------------------------------
__device__ __forceinline__ void gemmo_tile(int m0, int n0,
                                           const unsigned short* wo, const unsigned short* attnT,
                                           const float* bo, float* out,
                                           unsigned short* a_s, unsigned short* b_s, int tid){
    const int wave = tid >> 6, lane = tid & 63;
    const int l15 = lane & 15, l4 = lane >> 4;
    const int nw = wave * 32;
    const int r8 = lane >> 3, c8l = lane & 7;
    const int csw = (c8l ^ r8) * 8;
    const int rp = l15 & 7;
    const f32x4 vzero = {0.f, 0.f, 0.f, 0.f};
    f32x4 acc[4][2];
    #pragma unroll
    for (int i = 0; i < 4; i++){ acc[i][0] = vzero; acc[i][1] = vzero; }

    for (int k0 = 0; k0 < 512; k0 += 64){
        #pragma unroll
        for (int i = 0; i < 2; i++){               // A: 64 rows = 8 groups
            int rg = wave * 2 + i;
            gl2lds16(wo + (size_t)(m0 + rg*8 + r8) * 512 + k0 + csw, a_s + rg * 512);
        }
        #pragma unroll
        for (int i = 0; i < 4; i++){               // B: 128 rows = 16 groups
            int rg = wave * 4 + i;
            gl2lds16(attnT + (size_t)(n0 + rg*8 + r8) * 512 + k0 + csw, b_s + rg * 512);
        }
        __syncthreads();
        #pragma unroll
        for (int kk = 0; kk < 2; kk++){
            bf16x8 af[4], bfr[2];
            #pragma unroll
            for (int mt = 0; mt < 4; mt++)
                af[mt] = *(const bf16x8*)&a_s[(mt*16 + l15)*64 + (((kk*4) + l4) ^ rp)*8];
            #pragma unroll
            for (int ct = 0; ct < 2; ct++)
                bfr[ct] = *(const bf16x8*)&b_s[(nw + ct*16 + l15)*64 + (((kk*4) + l4) ^ rp)*8];
            #pragma unroll
            for (int mt = 0; mt < 4; mt++)
                #pragma unroll
                for (int ct = 0; ct < 2; ct++)
                    acc[mt][ct] = __builtin_amdgcn_mfma_f32_16x16x32_bf16(
                        af[mt], bfr[ct], acc[mt][ct], 0, 0, 0);
        }
        __syncthreads();
    }

    #pragma unroll
    for (int mt = 0; mt < 4; mt++){
        #pragma unroll
        for (int rr = 0; rr < 4; rr++){
            int row = m0 + mt*16 + l4*4 + rr;              // o index
            float bb = bo[row];
            #pragma unroll
            for (int ct2 = 0; ct2 < 2; ct2++){
                int n = n0 + nw + ct2*16 + l15;            // flat b*1024+t
                size_t oaddr = (size_t)(n >> 10) * 524288 + (size_t)row * 1024 + (n & 1023);
                out[oaddr] = acc[mt][ct2][rr] + bb;
            }
        }
    }
}

// ---------------- transpose/cvt unit body (R8-exact) --------------------------
__device__ __forceinline__ void transpose_unit(int u,
        const float* x, const float* c, const float* w0, const float* w1,
        const float* w2, const float* w3,
        unsigned short* xt, unsigned short* ct,
        unsigned short* o0, unsigned short* o1, unsigned short* o2, unsigned short* o3,
        float* tr, int tid){
    if (u >= 2048){                                // weight convert: fid as R8
        int fid = (u - 2048) * 256 + tid;
        const float* in; unsigned short* out;
        switch (fid >> 13){
            case 0: in = w0; out = o0; break;
            case 1: in = w1; out = o1; break;
            case 2: in = w2; out = o2; break;
            default: in = w3; out = o3; break;
        }
        int off = (fid & 8191) * 32;
        #pragma unroll
        for (int j = 0; j < 8; j++){
            float4 v = *(const float4*)(in + off + j*4);
            ushort4 o; o.x = f2bf(v.x); o.y = f2bf(v.y); o.z = f2bf(v.z); o.w = f2bf(v.w);
            *(ushort4*)(out + off + j*4) = o;
        }
        return;
    }
    const int z = u >> 7, rem = u & 127;
    const float* in = (z < 8) ? x : c;
    unsigned short* out = (z < 8) ? xt : ct;
    const int b = z & 7;
    const int t0 = (rem >> 3) * 64, c0 = (rem & 7) * 64;
    {
        int r = tid >> 2, q = (tid & 3) * 16;
        const float* src = in + ((size_t)b * 512 + c0 + r) * 1024 + t0 + q;
        #pragma unroll
        for (int j = 0; j < 4; j++)
            *(float4*)&tr[r*72 + q + j*4] = ((const float4*)src)[j];
    }
    __syncthreads();
    {
        int trr = tid >> 2, cj = (tid & 3) * 16;
        unsigned pw[8];
        #pragma unroll
        for (int j = 0; j < 8; j++){
            unsigned lo = f2bf(tr[(cj + 2*j    )*72 + trr]);
            unsigned hi = f2bf(tr[(cj + 2*j + 1)*72 + trr]);
            pw[j] = lo | (hi << 16);
        }
        unsigned short* dst = out + ((size_t)b * 1024 + t0 + trr) * 512 + c0 + cj;
        uint4 q0v = {pw[0], pw[1], pw[2], pw[3]};
        uint4 q1v = {pw[4], pw[5], pw[6], pw[7]};
        ((uint4*)dst)[0] = q0v;
        ((uint4*)dst)[1] = q1v;
    }
    __syncthreads();                               // LDS reuse across grid-stride units
}

// =================== fused cooperative kernel, grid = 512 =====================
__global__ __launch_bounds__(256, 2) void mha_fused(
        const float* __restrict__ x,  const float* __restrict__ c,
        const float* __restrict__ Wq, const float* __restrict__ bq,
        const float* __restrict__ Wk, const float* __restrict__ bk,
        const float* __restrict__ Wv, const float* __restrict__ bv,
        const float* __restrict__ Wo, const float* __restrict__ bo,
        unsigned short* __restrict__ wq_b, unsigned short* __restrict__ wk_b,
        unsigned short* __restrict__ wv_b, unsigned short* __restrict__ wo_b,
        unsigned short* __restrict__ xt,  unsigned short* __restrict__ ct,
        unsigned short* __restrict__ qt,  unsigned short* __restrict__ kt,
        unsigned short* __restrict__ vct, float* __restrict__ out){
    __shared__ SMem sm;
    cg::grid_group grid = cg::this_grid();
    const int bid = blockIdx.x, tid = threadIdx.x;
    unsigned short* attnT = xt;                    // xt dead after phase 1

    // phase 0: transpose+cvt (2048 tile units + 128 weight units)
    for (int u = bid; u < 2176; u += 512)
        transpose_unit(u, x, c, Wq, Wk, Wv, Wo, xt, ct, wq_b, wk_b, wv_b, wo_b, sm.tr, tid);
    grid.sync();

    // phase 1: qkv GEMMs, 768 R8-exact 128x128 tiles
    for (int u = bid; u < 768; u += 512)
        qkv_tile(u >> 8, u & 255, xt, ct, wq_b, wk_b, wv_b, bq, bk, bv,
                 qt, kt, vct, sm.g.a, sm.g.b, tid);
    grid.sync();

    // phase 2: flash attention, 512 tiles (bh-fastest swizzle)
    flash_tile((bid & 63) >> 3, bid & 7, (bid >> 6) * 128, qt, kt, vct, attnT, &sm.f, tid);
    grid.sync();

    // phase 3: output GEMM, 512 tiles
    gemmo_tile((bid & 7) * 64, (bid >> 3) * 128, wo_b, attnT, bo, out, sm.g.a, sm.g.b, tid);
}

// ===================== fallback path (R8 kernels, byte-identical math) ========
__global__ __launch_bounds__(256) void transpose_cvt(const float* __restrict__ x, const float* __restrict__ c,
                                                     const float* __restrict__ w0, const float* __restrict__ w1,
                                                     const float* __restrict__ w2, const float* __restrict__ w3,
                                                     unsigned short* __restrict__ xt, unsigned short* __restrict__ ct,
                                                     unsigned short* __restrict__ o0, unsigned short* __restrict__ o1,
                                                     unsigned short* __restrict__ o2, unsigned short* __restrict__ o3){
    __shared__ float tile[64*72];
    const int z = blockIdx.z;
    int u = (z == 16) ? 2048 + blockIdx.x * 8 + blockIdx.y
                      : z * 128 + blockIdx.x * 8 + blockIdx.y;
    transpose_unit(u, x, c, w0, w1, w2, w3, xt, ct, o0, o1, o2, o3, tile, threadIdx.x);
}

__global__ __launch_bounds__(256) void qkv_gemm(const unsigned short* __restrict__ xt,
                                                const unsigned short* __restrict__ ct,
                                                const unsigned short* __restrict__ wq,
                                                const unsigned short* __restrict__ wk,
                                                const unsigned short* __restrict__ wv,
                                                const float* __restrict__ bq_,
                                                const float* __restrict__ bk_,
                                                const float* __restrict__ bv_,
                                                unsigned short* __restrict__ qt,
                                                unsigned short* __restrict__ kt,
                                                unsigned short* __restrict__ vct){
    __shared__ SMemG sg;
    qkv_tile(blockIdx.y, blockIdx.x, xt, ct, wq, wk, wv, bq_, bk_, bv_,
             qt, kt, vct, sg.a, sg.b, threadIdx.x);
}

__global__ __launch_bounds__(256, 2) void flash_attn(const unsigned short* __restrict__ qt,
                                                     const unsigned short* __restrict__ kt,
                                                     const unsigned short* __restrict__ vct,
                                                     unsigned short* __restrict__ attnT){
    __shared__ SMemF sf;
    const int bhq = blockIdx.x;
    flash_tile((bhq & 63) >> 3, bhq & 7, (bhq >> 6) * 128, qt, kt, vct, attnT, &sf, threadIdx.x);
}

__global__ __launch_bounds__(256) void gemm_o(const unsigned short* __restrict__ wo,
                                              const unsigned short* __restrict__ attnT,
                                              const float* __restrict__ bo,
                                              float* __restrict__ out){
    __shared__ SMemG sg;
    gemmo_tile(blockIdx.x * 64, blockIdx.y * 128, wo, attnT, bo, out, sg.a, sg.b, threadIdx.x);
}

extern "C" void kernel_launch(void* const* d_in, const int* in_sizes, int n_in,
                              void* d_out, int out_size, void* d_ws, size_t ws_size,
                              hipStream_t stream){
    const float* x  = (const float*)d_in[0];
    const float* c  = (const float*)d_in[1];
    const float* Wq = (const float*)d_in[2];
    const float* bq = (const float*)d_in[3];
    const float* Wk = (const float*)d_in[4];
    const float* bk = (const float*)d_in[5];
    const float* Wv = (const float*)d_in[6];
    const float* bv = (const float*)d_in[7];
    const float* Wo = (const float*)d_in[8];
    const float* bo = (const float*)d_in[9];

    unsigned short* wq_b = (unsigned short*)d_ws;
    unsigned short* wk_b = wq_b + 262144;
    unsigned short* wv_b = wk_b + 262144;
    unsigned short* wo_b = wv_b + 262144;
    unsigned short* xt   = wo_b + 262144;
    unsigned short* ct   = xt  + 4194304;
    unsigned short* qt   = ct  + 4194304;
    unsigned short* kt   = qt  + 4194304;
    unsigned short* vct  = kt  + 4194304;
    float* outf = (float*)d_out;

    void* args[] = { (void*)&x, (void*)&c, (void*)&Wq, (void*)&bq, (void*)&Wk, (void*)&bk,
                     (void*)&Wv, (void*)&bv, (void*)&Wo, (void*)&bo,
                     (void*)&wq_b, (void*)&wk_b, (void*)&wv_b, (void*)&wo_b,
                     (void*)&xt, (void*)&ct, (void*)&qt, (void*)&kt, (void*)&vct, (void*)&outf };
    hipError_t err = hipLaunchCooperativeKernel((const void*)mha_fused, dim3(512), dim3(256),
                                                args, 0, stream);
    if (err != hipSuccess){
        // fallback: non-cooperative R8 path (identical math, passes at 171 us)
        unsigned short* attnT = xt;
        transpose_cvt<<<dim3(16, 8, 17), 256, 0, stream>>>(x, c, Wq, Wk, Wv, Wo,
                                                           xt, ct, wq_b, wk_b, wv_b, wo_b);
        qkv_gemm<<<dim3(256, 3), 256, 0, stream>>>(xt, ct, wq_b, wk_b, wv_b, bq, bk, bv, qt, kt, vct);
        flash_attn<<<dim3(512), 256, 0, stream>>>(qt, kt, vct, attnT);
        gemm_o<<<dim3(8, 64), 256, 0, stream>>>(wo_b, attnT, bo, (float*)d_out);
    }
}

// Round 10
// 168.827 us; speedup vs baseline: 2.4183x; 2.4183x over previous
//
#include <hip/hip_runtime.h>

typedef __bf16 bf16x8 __attribute__((ext_vector_type(8)));
typedef float  f32x4  __attribute__((ext_vector_type(4)));

__device__ __forceinline__ unsigned short f2bf(float f){
    union { float f; unsigned u; } v; v.f = f;
    v.u += 0x7fffu + ((v.u >> 16) & 1u);          // RNE
    return (unsigned short)(v.u >> 16);
}
__device__ __forceinline__ unsigned short f2bf_trunc(float f){
    union { float f; unsigned u; } v; v.f = f;
    return (unsigned short)(v.u >> 16);
}
// async 16B global->LDS. lptr wave-uniform; HW dest = lptr + lane*16.
__device__ __forceinline__ void gl2lds16(const unsigned short* g, unsigned short* l){
    __builtin_amdgcn_global_load_lds(
        (const __attribute__((address_space(1))) void*)g,
        (__attribute__((address_space(3))) void*)l, 16, 0, 0);
}

// ------- transpose+convert x,c AND weight convert, one launch -----------------
// z in [0,8): x slice b=z; z in [8,16): c slice b=z-8; z==16: the 4 weights.
__global__ __launch_bounds__(256) void transpose_cvt(const float* __restrict__ x, const float* __restrict__ c,
                                                     const float* __restrict__ w0, const float* __restrict__ w1,
                                                     const float* __restrict__ w2, const float* __restrict__ w3,
                                                     unsigned short* __restrict__ xt, unsigned short* __restrict__ ct,
                                                     unsigned short* __restrict__ o0, unsigned short* __restrict__ o1,
                                                     unsigned short* __restrict__ o2, unsigned short* __restrict__ o3){
    __shared__ float tile[64][72];
    const int z = blockIdx.z;
    if (z == 16){
        int fid = (blockIdx.x * 8 + blockIdx.y) * 256 + threadIdx.x;
        const float* in; unsigned short* out;
        switch (fid >> 13){
            case 0: in = w0; out = o0; break;
            case 1: in = w1; out = o1; break;
            case 2: in = w2; out = o2; break;
            default: in = w3; out = o3; break;
        }
        int off = (fid & 8191) * 32;
        #pragma unroll
        for (int j = 0; j < 8; j++){
            float4 v = *(const float4*)(in + off + j*4);
            ushort4 o; o.x = f2bf(v.x); o.y = f2bf(v.y); o.z = f2bf(v.z); o.w = f2bf(v.w);
            *(ushort4*)(out + off + j*4) = o;
        }
        return;
    }
    const float* in = (z < 8) ? x : c;
    unsigned short* out = (z < 8) ? xt : ct;
    const int b = z & 7;
    const int t0 = blockIdx.x * 64, c0 = blockIdx.y * 64;
    const int tid = threadIdx.x;
    {
        int r = tid >> 2, q = (tid & 3) * 16;
        const float* src = in + ((size_t)b * 512 + c0 + r) * 1024 + t0 + q;
        #pragma unroll
        for (int j = 0; j < 4; j++)
            *(float4*)&tile[r][q + j*4] = ((const float4*)src)[j];
    }
    __syncthreads();
    {
        int tr = tid >> 2, cj = (tid & 3) * 16;
        unsigned pw[8];
        #pragma unroll
        for (int j = 0; j < 8; j++){
            unsigned lo = f2bf(tile[cj + 2*j    ][tr]);
            unsigned hi = f2bf(tile[cj + 2*j + 1][tr]);
            pw[j] = lo | (hi << 16);
        }
        unsigned short* dst = out + ((size_t)b * 1024 + t0 + tr) * 512 + c0 + cj;
        uint4 q0 = {pw[0], pw[1], pw[2], pw[3]};
        uint4 q1 = {pw[4], pw[5], pw[6], pw[7]};
        ((uint4*)dst)[0] = q0;
        ((uint4*)dst)[1] = q1;
    }
}

// ============ R8-exact GEMM mainloop: 128x128 tile, K=512 =====================
// XOR-chunk swizzle: chunk c of row stored at position c^(row&7).
__device__ __forceinline__ void gemm_mainloop(const unsigned short* __restrict__ A,
                                              const unsigned short* __restrict__ Bm,
                                              unsigned short* a_s, unsigned short* b_s,
                                              int m0, int n0, int tid, f32x4 acc[4][4]){
    const int wave = tid >> 6, lane = tid & 63;
    const int l15 = lane & 15, l4 = lane >> 4;
    const int mw = (wave >> 1) * 64, nw = (wave & 1) * 64;
    const int r8 = lane >> 3, c8l = lane & 7;
    const int csw = (c8l ^ r8) * 8;                // swizzled source chunk (shorts)
    const int rp = l15 & 7;

    for (int k0 = 0; k0 < 512; k0 += 64){
        #pragma unroll
        for (int i = 0; i < 4; i++){
            int rg = i * 4 + wave;                 // 0..15 -> 8-row group
            int row = rg * 8 + r8;
            gl2lds16(A  + (size_t)(m0 + row) * 512 + k0 + csw, a_s + rg * 512);
            gl2lds16(Bm + (size_t)(n0 + row) * 512 + k0 + csw, b_s + rg * 512);
        }
        __syncthreads();
        #pragma unroll
        for (int kk = 0; kk < 2; kk++){
            bf16x8 af[4], bfr[4];
            #pragma unroll
            for (int mt = 0; mt < 4; mt++)
                af[mt] = *(const bf16x8*)&a_s[(mw + mt*16 + l15)*64 + (((kk*4) + l4) ^ rp)*8];
            #pragma unroll
            for (int ct = 0; ct < 4; ct++)
                bfr[ct] = *(const bf16x8*)&b_s[(nw + ct*16 + l15)*64 + (((kk*4) + l4) ^ rp)*8];
            #pragma unroll
            for (int mt = 0; mt < 4; mt++)
                #pragma unroll
                for (int ct = 0; ct < 4; ct++)
                    acc[mt][ct] = __builtin_amdgcn_mfma_f32_16x16x32_bf16(
                        af[mt], bfr[ct], acc[mt][ct], 0, 0, 0);
        }
        __syncthreads();
    }
}

// ---------------- merged QKV GEMM (R8-exact): blockIdx.y = z (0:q,1:k,2:v) ----
__global__ __launch_bounds__(256) void qkv_gemm(const unsigned short* __restrict__ xt,
                                                const unsigned short* __restrict__ ct,
                                                const unsigned short* __restrict__ wq,
                                                const unsigned short* __restrict__ wk,
                                                const unsigned short* __restrict__ wv,
                                                const float* __restrict__ bq_,
                                                const float* __restrict__ bk_,
                                                const float* __restrict__ bv_,
                                                unsigned short* __restrict__ qt,
                                                unsigned short* __restrict__ kt,
                                                unsigned short* __restrict__ vct){
    __shared__ unsigned short a_s[128*64];
    __shared__ unsigned short b_s[128*64];
    const int z = blockIdx.y, bid = blockIdx.x;
    const unsigned short *A, *Bm;
    int m0, n0;
    if (z == 0){ A = xt; Bm = wq; m0 = (bid >> 2)*128; n0 = (bid & 3)*128; }
    else if (z == 1){ A = ct; Bm = wk; m0 = (bid >> 2)*128; n0 = (bid & 3)*128; }
    else { A = wv; Bm = ct; m0 = (bid & 3)*128; n0 = (bid >> 2)*128; }
    const int tid = threadIdx.x;
    const int wave = tid >> 6, lane = tid & 63;
    const int l15 = lane & 15, l4 = lane >> 4;
    const int mw = (wave >> 1) * 64, nw = (wave & 1) * 64;
    const f32x4 vzero = {0.f, 0.f, 0.f, 0.f};
    f32x4 acc[4][4];
    #pragma unroll
    for (int i = 0; i < 4; i++)
        #pragma unroll
        for (int j = 0; j < 4; j++) acc[i][j] = vzero;

    gemm_mainloop(A, Bm, a_s, b_s, m0, n0, tid, acc);

    if (z < 2){
        unsigned short* out = (z == 0) ? qt : kt;
        const float* bias = (z == 0) ? bq_ : bk_;
        // q pre-scaled by (1/8)*log2(e) so flash uses exp2 directly
        const float osc = (z == 0) ? 0.1803368801111137f : 1.0f;
        float bv4[4];
        #pragma unroll
        for (int ct2 = 0; ct2 < 4; ct2++) bv4[ct2] = bias[n0 + nw + ct2*16 + l15];
        const float theta = __powf(10000.0f, -(float)l15 * (1.0f / 16.0f));
        #pragma unroll
        for (int mt = 0; mt < 4; mt++){
            #pragma unroll
            for (int rr = 0; rr < 4; rr++){
                int row = m0 + mw + mt*16 + l4*4 + rr;     // flat b*1024+t
                int t = row & 1023;
                float v[4];
                #pragma unroll
                for (int ct2 = 0; ct2 < 4; ct2++) v[ct2] = acc[mt][ct2][rr] + bv4[ct2];
                float sn, cn;
                __sincosf((float)t * theta, &sn, &cn);
                float r0 = v[0] * cn - v[1] * sn;
                float r1 = v[1] * cn + v[0] * sn;
                v[0] = r0; v[1] = r1;
                #pragma unroll
                for (int ct2 = 0; ct2 < 4; ct2++)
                    out[(size_t)row * 512 + n0 + nw + ct2*16 + l15] = f2bf(v[ct2] * osc);
            }
        }
    } else {
        #pragma unroll
        for (int mt = 0; mt < 4; mt++){
            #pragma unroll
            for (int rr = 0; rr < 4; rr++){
                int row = m0 + mw + mt*16 + l4*4 + rr;     // o index
                float bb = bv_[row];
                #pragma unroll
                for (int ct2 = 0; ct2 < 4; ct2++){
                    int n = n0 + nw + ct2*16 + l15;        // flat b*1024+t
                    size_t oaddr = (size_t)(n >> 10) * 524288 + (size_t)row * 1024 + (n & 1023);
                    vct[oaddr] = f2bf(acc[mt][ct2][rr] + bb);
                }
            }
        }
    }
}

// ---------------- final GEMM (R8-exact): out = Wo*attnT^T + bo, f32 -----------
// 64x128 tile, grid 8x64 = 512 blocks.
__global__ __launch_bounds__(256) void gemm_o(const unsigned short* __restrict__ wo,
                                              const unsigned short* __restrict__ attnT,
                                              const float* __restrict__ bo,
                                              float* __restrict__ out){
    __shared__ unsigned short a_s[64*64];
    __shared__ unsigned short b_s[128*64];
    const int m0 = blockIdx.x * 64, n0 = blockIdx.y * 128;
    const int tid = threadIdx.x;
    const int wave = tid >> 6, lane = tid & 63;
    const int l15 = lane & 15, l4 = lane >> 4;
    const int nw = wave * 32;
    const int r8 = lane >> 3, c8l = lane & 7;
    const int csw = (c8l ^ r8) * 8;
    const int rp = l15 & 7;
    const f32x4 vzero = {0.f, 0.f, 0.f, 0.f};
    f32x4 acc[4][2];
    #pragma unroll
    for (int i = 0; i < 4; i++){ acc[i][0] = vzero; acc[i][1] = vzero; }

    for (int k0 = 0; k0 < 512; k0 += 64){
        #pragma unroll
        for (int i = 0; i < 2; i++){               // A: 64 rows = 8 groups
            int rg = wave * 2 + i;
            gl2lds16(wo + (size_t)(m0 + rg*8 + r8) * 512 + k0 + csw, a_s + rg * 512);
        }
        #pragma unroll
        for (int i = 0; i < 4; i++){               // B: 128 rows = 16 groups
            int rg = wave * 4 + i;
            gl2lds16(attnT + (size_t)(n0 + rg*8 + r8) * 512 + k0 + csw, b_s + rg * 512);
        }
        __syncthreads();
        #pragma unroll
        for (int kk = 0; kk < 2; kk++){
            bf16x8 af[4], bfr[2];
            #pragma unroll
            for (int mt = 0; mt < 4; mt++)
                af[mt] = *(const bf16x8*)&a_s[(mt*16 + l15)*64 + (((kk*4) + l4) ^ rp)*8];
            #pragma unroll
            for (int ct = 0; ct < 2; ct++)
                bfr[ct] = *(const bf16x8*)&b_s[(nw + ct*16 + l15)*64 + (((kk*4) + l4) ^ rp)*8];
            #pragma unroll
            for (int mt = 0; mt < 4; mt++)
                #pragma unroll
                for (int ct = 0; ct < 2; ct++)
                    acc[mt][ct] = __builtin_amdgcn_mfma_f32_16x16x32_bf16(
                        af[mt], bfr[ct], acc[mt][ct], 0, 0, 0);
        }
        __syncthreads();
    }

    #pragma unroll
    for (int mt = 0; mt < 4; mt++){
        #pragma unroll
        for (int rr = 0; rr < 4; rr++){
            int row = m0 + mt*16 + l4*4 + rr;              // o index
            float bb = bo[row];
            #pragma unroll
            for (int ct2 = 0; ct2 < 2; ct2++){
                int n = n0 + nw + ct2*16 + l15;            // flat b*1024+t
                size_t oaddr = (size_t)(n >> 10) * 524288 + (size_t)row * 1024 + (n & 1023);
                out[oaddr] = acc[mt][ct2][rr] + bb;
            }
        }
    }
}

// ---------------- flash attention (R8 math + per-strip P double-buffer) -------
// Block = (b,h, 128 q-rows). Flat grid 512, bh-fastest swizzle.
// p_s[wave][st]: separate P scratch per strip removes the LDS WAR ordering
// between strip0's ds_read_b128 and strip1's stores -> strips can interleave.
__global__ __launch_bounds__(256, 2) void flash_attn(const unsigned short* __restrict__ qt,
                                                     const unsigned short* __restrict__ kt,
                                                     const unsigned short* __restrict__ vct,
                                                     unsigned short* __restrict__ attnT){
    __shared__ unsigned short k_s[2][64*64];
    __shared__ unsigned short v_s[2][64*64];
    __shared__ unsigned short p_s[4][2][16*72];
    const int bhq = blockIdx.x;
    const int bh = bhq & 63, b = bh >> 3, h = bh & 7;
    const int q0 = (bhq >> 6) * 128;
    const int tid = threadIdx.x, wave = tid >> 6, lane = tid & 63;
    const int l15 = lane & 15, l4 = lane >> 4;
    const int r8 = lane >> 3, c8l = lane & 7;
    const int csw = (c8l ^ r8) * 8;
    const int rp = l15 & 7;
    const f32x4 vzero = {0.f, 0.f, 0.f, 0.f};
    const unsigned short* kbase = kt  + (size_t)(b*1024)*512 + h*64;
    const unsigned short* vbase = vct + (size_t)(b*512 + h*64)*1024;

    bf16x8 qf[2][2];
    #pragma unroll
    for (int st = 0; st < 2; st++)
        #pragma unroll
        for (int kh = 0; kh < 2; kh++)
            qf[st][kh] = *(const bf16x8*)(qt + (size_t)(b*1024 + q0 + wave*32 + st*16 + l15)*512
                                             + h*64 + kh*32 + l4*8);
    f32x4 o_acc[2][4], l_acc[2];
    #pragma unroll
    for (int st = 0; st < 2; st++){
        l_acc[st] = vzero;
        #pragma unroll
        for (int dt = 0; dt < 4; dt++) o_acc[st][dt] = vzero;
    }
    const __bf16 one_bf = (__bf16)1.0f;
    const bf16x8 ones = {one_bf, one_bf, one_bf, one_bf, one_bf, one_bf, one_bf, one_bf};

    auto stage = [&](int tile, int buf){
        const int s0n = tile * 64;
        #pragma unroll
        for (int i = 0; i < 2; i++){
            int rg = i * 4 + wave;
            int row = rg * 8 + r8;
            gl2lds16(kbase + (size_t)(s0n + row)*512 + csw, &k_s[buf][rg*512]);
            gl2lds16(vbase + (size_t)row*1024 + s0n + csw, &v_s[buf][rg*512]);
        }
    };
    stage(0, 0);
    __syncthreads();

    for (int it = 0; it < 16; ++it){
        const int cur = it & 1;
        if (it < 15) stage(it + 1, cur ^ 1);
        bf16x8 kf[2][4], vf[2][4];
        #pragma unroll
        for (int kh = 0; kh < 2; kh++)
            #pragma unroll
            for (int ct = 0; ct < 4; ct++)
                kf[kh][ct] = *(const bf16x8*)&k_s[cur][(ct*16 + l15)*64 + ((kh*4 + l4) ^ rp)*8];
        #pragma unroll
        for (int sh = 0; sh < 2; sh++)
            #pragma unroll
            for (int dt = 0; dt < 4; dt++)
                vf[sh][dt] = *(const bf16x8*)&v_s[cur][(dt*16 + l15)*64 + ((sh*4 + l4) ^ rp)*8];
        #pragma unroll
        for (int st = 0; st < 2; st++){
            f32x4 sa[4];
            #pragma unroll
            for (int ct = 0; ct < 4; ct++) sa[ct] = vzero;
            #pragma unroll
            for (int kh = 0; kh < 2; kh++)
                #pragma unroll
                for (int ct = 0; ct < 4; ct++)
                    sa[ct] = __builtin_amdgcn_mfma_f32_16x16x32_bf16(qf[st][kh], kf[kh][ct], sa[ct], 0, 0, 0);
            #pragma unroll
            for (int ct = 0; ct < 4; ct++)
                #pragma unroll
                for (int rr = 0; rr < 4; rr++)
                    sa[ct][rr] = exp2f(sa[ct][rr]);        // q carries log2e/8
            #pragma unroll
            for (int ct = 0; ct < 4; ct++)
                #pragma unroll
                for (int rr = 0; rr < 4; rr++)
                    p_s[wave][st][(l4*4 + rr)*72 + ct*16 + l15] = f2bf_trunc(sa[ct][rr]);
            bf16x8 ap0 = *(const bf16x8*)&p_s[wave][st][l15*72 + l4*8];
            bf16x8 ap1 = *(const bf16x8*)&p_s[wave][st][l15*72 + 32 + l4*8];
            l_acc[st] = __builtin_amdgcn_mfma_f32_16x16x32_bf16(ap0, ones, l_acc[st], 0, 0, 0);
            l_acc[st] = __builtin_amdgcn_mfma_f32_16x16x32_bf16(ap1, ones, l_acc[st], 0, 0, 0);
            #pragma unroll
            for (int dt = 0; dt < 4; dt++){
                o_acc[st][dt] = __builtin_amdgcn_mfma_f32_16x16x32_bf16(ap0, vf[0][dt], o_acc[st][dt], 0, 0, 0);
                o_acc[st][dt] = __builtin_amdgcn_mfma_f32_16x16x32_bf16(ap1, vf[1][dt], o_acc[st][dt], 0, 0, 0);
            }
        }
        __syncthreads();
    }
    #pragma unroll
    for (int st = 0; st < 2; st++){
        float rl[4];
        #pragma unroll
        for (int rr = 0; rr < 4; rr++) rl[rr] = __builtin_amdgcn_rcpf(l_acc[st][rr]);
        #pragma unroll
        for (int dt = 0; dt < 4; dt++)
            #pragma unroll
            for (int rr = 0; rr < 4; rr++){
                int row = q0 + wave*32 + st*16 + l4*4 + rr;
                attnT[(size_t)(b*1024 + row)*512 + h*64 + dt*16 + l15] = f2bf(o_acc[st][dt][rr] * rl[rr]);
            }
    }
}

extern "C" void kernel_launch(void* const* d_in, const int* in_sizes, int n_in,
                              void* d_out, int out_size, void* d_ws, size_t ws_size,
                              hipStream_t stream){
    const float* x  = (const float*)d_in[0];
    const float* c  = (const float*)d_in[1];
    const float* Wq = (const float*)d_in[2];
    const float* bq = (const float*)d_in[3];
    const float* Wk = (const float*)d_in[4];
    const float* bk = (const float*)d_in[5];
    const float* Wv = (const float*)d_in[6];
    const float* bv = (const float*)d_in[7];
    const float* Wo = (const float*)d_in[8];
    const float* bo = (const float*)d_in[9];

    unsigned short* wq_b = (unsigned short*)d_ws;
    unsigned short* wk_b = wq_b + 262144;
    unsigned short* wv_b = wk_b + 262144;
    unsigned short* wo_b = wv_b + 262144;
    unsigned short* xt   = wo_b + 262144;
    unsigned short* ct   = xt  + 4194304;
    unsigned short* qt   = ct  + 4194304;
    unsigned short* kt   = qt  + 4194304;
    unsigned short* vct  = kt  + 4194304;
    unsigned short* attnT = xt;                            // xt dead after q-GEMM

    transpose_cvt<<<dim3(16, 8, 17), 256, 0, stream>>>(x, c, Wq, Wk, Wv, Wo,
                                                       xt, ct, wq_b, wk_b, wv_b, wo_b);
    qkv_gemm<<<dim3(256, 3), 256, 0, stream>>>(xt, ct, wq_b, wk_b, wv_b, bq, bk, bv, qt, kt, vct);
    flash_attn<<<dim3(512), 256, 0, stream>>>(qt, kt, vct, attnT);
    gemm_o<<<dim3(8, 64), 256, 0, stream>>>(wo_b, attnT, bo, (float*)d_out);
}